// Round 5
// baseline (516.352 us; speedup 1.0000x reference)
//
#include <hip/hip_runtime.h>

// Problem constants: N=50000, E=600000, F=128, H=128, O=64, R=8
#define F_DIM 128
#define H_DIM 128
#define O_DIM 64
#define R_NUM 8
#define KTOT 1152   // 9 * 128 stacked K (8 relations + root/self)

typedef __attribute__((ext_vector_type(8))) short bf16x8;
typedef __attribute__((ext_vector_type(4))) float f32x4;
typedef __attribute__((ext_vector_type(8))) unsigned short u16x8;
typedef __attribute__((ext_vector_type(4))) unsigned short u16x4;

__device__ __forceinline__ unsigned short f2b(float f) {
    unsigned u = __float_as_uint(f);
    u += 0x7FFFu + ((u >> 16) & 1u);   // RNE
    return (unsigned short)(u >> 16);
}
__device__ __forceinline__ float b2f(unsigned short b) {
    return __uint_as_float(((unsigned)b) << 16);
}

// ---------------- init min/max cell ----------------
__global__ void init_mm(float* mm) {
    if (threadIdx.x == 0) {
        ((int*)mm)[0] = 0x7f800000;  // +inf
        ((int*)mm)[1] = 0x00000000;  // 0.0f (weights >= 0)
    }
}

// ---------------- fused: (dst,rel) degree count + edge-weight min/max ----------
__global__ void count_minmax(const float* __restrict__ ew, const int* __restrict__ dst,
                             const int* __restrict__ et, int* __restrict__ deg2,
                             float* __restrict__ mm, int E) {
    __shared__ float smn[256], smx[256];
    int tid = threadIdx.x;
    float mn = 1e30f, mx = -1e30f;
    for (int i = blockIdx.x * blockDim.x + tid; i < E; i += gridDim.x * blockDim.x) {
        atomicAdd(&deg2[dst[i] * R_NUM + et[i]], 1);
        float v = ew[i];
        mn = fminf(mn, v);
        mx = fmaxf(mx, v);
    }
    smn[tid] = mn; smx[tid] = mx;
    __syncthreads();
    for (int s = 128; s > 0; s >>= 1) {
        if (tid < s) {
            smn[tid] = fminf(smn[tid], smn[tid + s]);
            smx[tid] = fmaxf(smx[tid], smx[tid + s]);
        }
        __syncthreads();
    }
    if (tid == 0) {
        atomicMin((int*)mm + 0, __float_as_int(smn[0]));
        atomicMax((int*)mm + 1, __float_as_int(smx[0]));
    }
}

// node inverse-degree from deg2 row sums
__global__ void invert2_kernel(const int* __restrict__ deg2, float* __restrict__ invc, int N) {
    int n = blockIdx.x * blockDim.x + threadIdx.x;
    if (n >= N) return;
    const int4* p = (const int4*)(deg2 + (size_t)n * R_NUM);
    int4 a = p[0], b = p[1];
    int s = a.x + a.y + a.z + a.w + b.x + b.y + b.z + b.w;
    invc[n] = 1.0f / (float)max(s, 1);
}

// ---------------- conversions ----------------
__global__ void convert_bf16(const float* __restrict__ in, unsigned short* __restrict__ out,
                             long n4) {
    long i = (long)blockIdx.x * blockDim.x + threadIdx.x;
    if (i >= n4) return;
    float4 v = ((const float4*)in)[i];
    ushort4 o;
    o.x = f2b(v.x); o.y = f2b(v.y); o.z = f2b(v.z); o.w = f2b(v.w);
    ((ushort4*)out)[i] = o;
}

// W [8][K][Ncol] + root [K][Ncol] -> Wt [9][Ncol][K] bf16 (transposed)
__global__ void conv_wt(const float* __restrict__ W, const float* __restrict__ root,
                        unsigned short* __restrict__ Wt, int K, int Ncol) {
    int idx = blockIdx.x * blockDim.x + threadIdx.x;
    int total = 9 * K * Ncol;
    if (idx >= total) return;
    int r = idx / (K * Ncol);
    int rem = idx % (K * Ncol);
    int n = rem / K;
    int k = rem % K;
    float v = (r < 8) ? W[((size_t)r * K + k) * Ncol + n] : root[(size_t)k * Ncol + n];
    Wt[idx] = f2b(v);
}

// ---------------- scan over M=N*8 (2048 elems / block) ----------------
__global__ void scan1_kernel(const int* __restrict__ deg, int* __restrict__ rp,
                             int* __restrict__ bsum, int M) {
    __shared__ int s[256];
    int base = blockIdx.x * 2048;
    int t = threadIdx.x;
    int v[8]; int loc = 0;
#pragma unroll
    for (int i = 0; i < 8; ++i) {
        int idx = base + t * 8 + i;
        v[i] = (idx < M) ? deg[idx] : 0;
        loc += v[i];
    }
    s[t] = loc;
    __syncthreads();
    for (int off = 1; off < 256; off <<= 1) {
        int x = (t >= off) ? s[t - off] : 0;
        __syncthreads();
        s[t] += x;
        __syncthreads();
    }
    int run = s[t] - loc;
#pragma unroll
    for (int i = 0; i < 8; ++i) {
        int idx = base + t * 8 + i;
        if (idx < M) rp[idx] = run;
        run += v[i];
    }
    if (t == 255) bsum[blockIdx.x] = s[255];
}

// parallel exclusive scan of bsum (nb <= 256)
__global__ void scan2_kernel(int* bsum, int nb) {
    __shared__ int s[256];
    int t = threadIdx.x;
    int v = (t < nb) ? bsum[t] : 0;
    s[t] = v;
    __syncthreads();
    for (int off = 1; off < 256; off <<= 1) {
        int x = (t >= off) ? s[t - off] : 0;
        __syncthreads();
        s[t] += x;
        __syncthreads();
    }
    if (t < nb) bsum[t] = s[t] - v;
}

__global__ void scan3_kernel(int* __restrict__ rp, const int* __restrict__ bsum, int M) {
    int i = blockIdx.x * blockDim.x + threadIdx.x;
    if (i < M) rp[i] += bsum[i >> 11];
}

// ---------------- CSR fill: pos = rp2[dst*8+rel]++ ; erec = {src, w_norm} -----
__global__ void fill2_kernel(const int* __restrict__ src, const int* __restrict__ dst,
                             const int* __restrict__ et, const float* __restrict__ ew,
                             const float* __restrict__ mm, int* __restrict__ rp2,
                             int2* __restrict__ erec, int E) {
    int e = blockIdx.x * blockDim.x + threadIdx.x;
    if (e >= E) return;
    int pos = atomicAdd(&rp2[dst[e] * R_NUM + et[e]], 1);
    float mn = mm[0], mx = mm[1];
    erec[pos] = make_int2(src[e], __float_as_int((ew[e] - mn) / (mx - mn + 1e-8f)));
}

// ---------------- gather: y[n][r] = invc[n] * sum_{e in (n,r)} w * xb[src] ----
// y[n][8] = xb[n] (self/root slot). 16 lanes per (n,r) group, 8 ch each.
// Writes fully coalesced (group covers 256B contiguous; groups contiguous).
__global__ void gather_y(const int* __restrict__ rp2, const int2* __restrict__ erec,
                         const unsigned short* __restrict__ xb,
                         const float* __restrict__ invc,
                         unsigned short* __restrict__ y, int N) {
    int gid = blockIdx.x * blockDim.x + threadIdx.x;
    int grp = gid >> 4;
    int n = grp / 9;
    if (n >= N) return;
    int r = grp - n * 9;
    int j = (gid & 15) * 8;
    unsigned short* dstp = y + (size_t)n * KTOT + r * 128 + j;
    if (r == 8) {
        *(u16x8*)dstp = *(const u16x8*)(xb + (size_t)n * 128 + j);
        return;
    }
    int i = n * R_NUM + r;
    int beg = (i == 0) ? 0 : rp2[i - 1];
    int end = rp2[i];
    float acc[8] = {0.f, 0.f, 0.f, 0.f, 0.f, 0.f, 0.f, 0.f};
    for (int k = beg; k < end; ++k) {
        int2 e = erec[k];
        float w = __int_as_float(e.y);
        const u16x8 v = *(const u16x8*)(xb + (size_t)e.x * 128 + j);
#pragma unroll
        for (int c = 0; c < 8; ++c) acc[c] += w * b2f(v[c]);
    }
    float inv = invc[n];
    u16x8 o;
#pragma unroll
    for (int c = 0; c < 8; ++c) o[c] = f2b(acc[c] * inv);
    *(u16x8*)dstp = o;
}

// ---------------- stacked GEMM: out[n] = y[n] (1x1152) @ W' (1152xNCOL) + bias -
// Role-swapped MFMA: A = W' frags (rows=outcols), B = y frags (cols=nodes).
// D: col(lane&15)=node, row(quad*4+i)=outcol.
template <int NCOL, bool RELU, bool OUTB>
__global__ __launch_bounds__(256) void gemm_y(const unsigned short* __restrict__ y,
                                              const unsigned short* __restrict__ Wt,
                                              const float* __restrict__ bias,
                                              unsigned short* __restrict__ outb,
                                              float* __restrict__ outf, int M) {
    constexpr int NT = NCOL / 16;
    const int wave = threadIdx.x >> 6, lane = threadIdx.x & 63;
    const int quad = lane >> 4, l15 = lane & 15;
    const int n0 = blockIdx.x * 64 + wave * 16;
    int nld = n0 + l15;
    if (nld >= M) nld = M - 1;
    const unsigned short* yrow = y + (size_t)nld * KTOT + quad * 8;

    f32x4 acc[NT];
#pragma unroll
    for (int nt = 0; nt < NT; ++nt) acc[nt] = (f32x4){0.f, 0.f, 0.f, 0.f};

#pragma unroll
    for (int kk = 0; kk < 36; ++kk) {
        const int r = kk >> 2, k2 = kk & 3;
        bf16x8 b = *(const bf16x8*)(yrow + r * 128 + k2 * 32);
#pragma unroll
        for (int nt = 0; nt < NT; ++nt) {
            bf16x8 a = *(const bf16x8*)(Wt + ((size_t)(r * NCOL + nt * 16 + l15)) * 128
                                        + k2 * 32 + quad * 8);
            acc[nt] = __builtin_amdgcn_mfma_f32_16x16x32_bf16(a, b, acc[nt], 0, 0, 0);
        }
    }

    const int node = n0 + l15;
    if (node < M) {
#pragma unroll
        for (int nt = 0; nt < NT; ++nt) {
            int c0 = nt * 16 + quad * 4;
            float4 bs = *(const float4*)(bias + c0);
            float v0 = acc[nt][0] + bs.x;
            float v1 = acc[nt][1] + bs.y;
            float v2 = acc[nt][2] + bs.z;
            float v3 = acc[nt][3] + bs.w;
            if (RELU) {
                v0 = fmaxf(v0, 0.f); v1 = fmaxf(v1, 0.f);
                v2 = fmaxf(v2, 0.f); v3 = fmaxf(v3, 0.f);
            }
            if (OUTB) {
                u16x4 o = {f2b(v0), f2b(v1), f2b(v2), f2b(v3)};
                *(u16x4*)(outb + (size_t)node * NCOL + c0) = o;
            } else {
                *(float4*)(outf + (size_t)node * NCOL + c0) = make_float4(v0, v1, v2, v3);
            }
        }
    }
}

extern "C" void kernel_launch(void* const* d_in, const int* in_sizes, int n_in,
                              void* d_out, int out_size, void* d_ws, size_t ws_size,
                              hipStream_t stream) {
    const float* x     = (const float*)d_in[0];
    const int*   ei    = (const int*)d_in[1];
    const float* ew    = (const float*)d_in[2];
    const int*   et    = (const int*)d_in[3];
    const float* W1    = (const float*)d_in[4];
    const float* root1 = (const float*)d_in[5];
    const float* bias1 = (const float*)d_in[6];
    const float* W2    = (const float*)d_in[7];
    const float* root2 = (const float*)d_in[8];
    const float* bias2 = (const float*)d_in[9];

    const int N = in_sizes[0] / F_DIM;
    const int E = in_sizes[2];
    const int M2 = N * R_NUM;
    const int* srcp = ei;
    const int* dstp = ei + E;

    // ws layout (int units unless noted):
    // mm[16] | invc[N] | deg2[8N] | rp2[8N] | bsum[256] | erec[2E int] |
    // xb[N*128 u16] | hb[N*128 u16] | wt1[9*128*128 u16] | wt2[9*64*128 u16] |
    // y[N*1152 u16]       total ~150 MB
    int* base = (int*)d_ws;
    float* mm    = (float*)base;
    float* invc  = (float*)(base + 16);
    int*   deg2  = base + 16 + N;
    int*   rp2   = deg2 + M2;
    int*   bsum  = rp2 + M2;
    int2*  erec  = (int2*)(bsum + 256);
    unsigned short* xb  = (unsigned short*)(bsum + 256 + 2 * E);
    unsigned short* hb  = xb + (size_t)N * 128;
    unsigned short* wt1 = hb + (size_t)N * 128;
    unsigned short* wt2 = wt1 + 9 * 128 * 128;
    unsigned short* y   = wt2 + 9 * 64 * 128;   // N * 1152

    const int TB = 256;
    int blocksE = (E + TB - 1) / TB;
    int blocksN = (N + TB - 1) / TB;
    int nb = (M2 + 2047) / 2048;   // 196 <= 256

    // ---- setup ----
    init_mm<<<1, 64, 0, stream>>>(mm);
    hipMemsetAsync(deg2, 0, (size_t)M2 * sizeof(int), stream);
    count_minmax<<<512, TB, 0, stream>>>(ew, dstp, et, deg2, mm, E);
    long x4 = (long)N * 128 / 4;
    convert_bf16<<<(int)((x4 + TB - 1) / TB), TB, 0, stream>>>(x, xb, x4);
    int wt1n = 9 * 128 * 128, wt2n = 9 * 64 * 128;
    conv_wt<<<(wt1n + TB - 1) / TB, TB, 0, stream>>>(W1, root1, wt1, F_DIM, H_DIM);
    conv_wt<<<(wt2n + TB - 1) / TB, TB, 0, stream>>>(W2, root2, wt2, H_DIM, O_DIM);
    scan1_kernel<<<nb, TB, 0, stream>>>(deg2, rp2, bsum, M2);
    scan2_kernel<<<1, TB, 0, stream>>>(bsum, nb);
    scan3_kernel<<<(M2 + TB - 1) / TB, TB, 0, stream>>>(rp2, bsum, M2);
    invert2_kernel<<<blocksN, TB, 0, stream>>>(deg2, invc, N);
    fill2_kernel<<<blocksE, TB, 0, stream>>>(srcp, dstp, et, ew, mm, rp2, erec, E);

    int gatB = (int)(((long)N * 9 * 16 + TB - 1) / TB);   // 28125
    int gB = (N + 63) / 64;                               // 782

    // ---- layer 1: gather y from xb ; out = y @ [W1;root1] + bias1, relu -> hb
    gather_y<<<gatB, TB, 0, stream>>>(rp2, erec, xb, invc, y, N);
    gemm_y<H_DIM, true, true><<<gB, TB, 0, stream>>>(y, wt1, bias1, hb, nullptr, N);

    // ---- layer 2: gather y from hb ; out = y @ [W2;root2] + bias2 -> d_out
    gather_y<<<gatB, TB, 0, stream>>>(rp2, erec, hb, invc, y, N);
    gemm_y<O_DIM, false, false><<<gB, TB, 0, stream>>>(y, wt2, bias2, nullptr,
                                                       (float*)d_out, N);
}

// Round 6
// 367.840 us; speedup vs baseline: 1.4037x; 1.4037x over previous
//
#include <hip/hip_runtime.h>

// Problem constants: N=50000, E=600000, F=128, H=128, O=64, R=8
#define F_DIM 128
#define H_DIM 128
#define O_DIM 64
#define R_NUM 8

typedef __attribute__((ext_vector_type(8))) short bf16x8;
typedef __attribute__((ext_vector_type(4))) float f32x4;

union V8 { bf16x8 v; short4 h[2]; };

__device__ __forceinline__ unsigned short f2b(float f) {
    unsigned u = __float_as_uint(f);
    u += 0x7FFFu + ((u >> 16) & 1u);   // RNE
    return (unsigned short)(u >> 16);
}
__device__ __forceinline__ float b2f(unsigned short b) {
    return __uint_as_float(((unsigned)b) << 16);
}

// ---------------- init min/max cell ----------------
__global__ void init_mm(float* mm) {
    if (threadIdx.x == 0) {
        ((int*)mm)[0] = 0x7f800000;  // +inf
        ((int*)mm)[1] = 0x00000000;  // 0.0f (weights >= 0)
    }
}

// ---------------- fused: (dst,rel) degree count + edge-weight min/max ----------
__global__ void count_minmax(const float* __restrict__ ew, const int* __restrict__ dst,
                             const int* __restrict__ et, int* __restrict__ deg2,
                             float* __restrict__ mm, int E) {
    __shared__ float smn[256], smx[256];
    int tid = threadIdx.x;
    float mn = 1e30f, mx = -1e30f;
    for (int i = blockIdx.x * blockDim.x + tid; i < E; i += gridDim.x * blockDim.x) {
        atomicAdd(&deg2[dst[i] * R_NUM + et[i]], 1);
        float v = ew[i];
        mn = fminf(mn, v);
        mx = fmaxf(mx, v);
    }
    smn[tid] = mn; smx[tid] = mx;
    __syncthreads();
    for (int s = 128; s > 0; s >>= 1) {
        if (tid < s) {
            smn[tid] = fminf(smn[tid], smn[tid + s]);
            smx[tid] = fmaxf(smx[tid], smx[tid + s]);
        }
        __syncthreads();
    }
    if (tid == 0) {
        atomicMin((int*)mm + 0, __float_as_int(smn[0]));
        atomicMax((int*)mm + 1, __float_as_int(smx[0]));
    }
}

// node inverse-degree from deg2 row sums
__global__ void invert2_kernel(const int* __restrict__ deg2, float* __restrict__ invc, int N) {
    int n = blockIdx.x * blockDim.x + threadIdx.x;
    if (n >= N) return;
    const int4* p = (const int4*)(deg2 + (size_t)n * R_NUM);
    int4 a = p[0], b = p[1];
    int s = a.x + a.y + a.z + a.w + b.x + b.y + b.z + b.w;
    invc[n] = 1.0f / (float)max(s, 1);
}

// ---------------- conversions ----------------
__global__ void convert_bf16(const float* __restrict__ in, unsigned short* __restrict__ out,
                             long n4) {
    long i = (long)blockIdx.x * blockDim.x + threadIdx.x;
    if (i >= n4) return;
    float4 v = ((const float4*)in)[i];
    ushort4 o;
    o.x = f2b(v.x); o.y = f2b(v.y); o.z = f2b(v.z); o.w = f2b(v.w);
    ((ushort4*)out)[i] = o;
}

// W [8][K][Ncol] + root [K][Ncol] -> Wt [9][Ncol][K] bf16 (transposed)
__global__ void conv_wt(const float* __restrict__ W, const float* __restrict__ root,
                        unsigned short* __restrict__ Wt, int K, int Ncol) {
    int idx = blockIdx.x * blockDim.x + threadIdx.x;
    int total = 9 * K * Ncol;
    if (idx >= total) return;
    int r = idx / (K * Ncol);
    int rem = idx % (K * Ncol);
    int n = rem / K;
    int k = rem % K;
    float v = (r < 8) ? W[((size_t)r * K + k) * Ncol + n] : root[(size_t)k * Ncol + n];
    Wt[idx] = f2b(v);
}

// ---------------- scan over M=N*8 (2048 elems / block) ----------------
__global__ void scan1_kernel(const int* __restrict__ deg, int* __restrict__ rp,
                             int* __restrict__ bsum, int M) {
    __shared__ int s[256];
    int base = blockIdx.x * 2048;
    int t = threadIdx.x;
    int v[8]; int loc = 0;
#pragma unroll
    for (int i = 0; i < 8; ++i) {
        int idx = base + t * 8 + i;
        v[i] = (idx < M) ? deg[idx] : 0;
        loc += v[i];
    }
    s[t] = loc;
    __syncthreads();
    for (int off = 1; off < 256; off <<= 1) {
        int x = (t >= off) ? s[t - off] : 0;
        __syncthreads();
        s[t] += x;
        __syncthreads();
    }
    int run = s[t] - loc;
#pragma unroll
    for (int i = 0; i < 8; ++i) {
        int idx = base + t * 8 + i;
        if (idx < M) rp[idx] = run;
        run += v[i];
    }
    if (t == 255) bsum[blockIdx.x] = s[255];
}

__global__ void scan2_kernel(int* bsum, int nb) {
    __shared__ int s[256];
    int t = threadIdx.x;
    int v = (t < nb) ? bsum[t] : 0;
    s[t] = v;
    __syncthreads();
    for (int off = 1; off < 256; off <<= 1) {
        int x = (t >= off) ? s[t - off] : 0;
        __syncthreads();
        s[t] += x;
        __syncthreads();
    }
    if (t < nb) bsum[t] = s[t] - v;
}

__global__ void scan3_kernel(int* __restrict__ rp, const int* __restrict__ bsum, int M) {
    int i = blockIdx.x * blockDim.x + threadIdx.x;
    if (i < M) rp[i] += bsum[i >> 11];
}

// ---------------- CSR fill: pos = rp2[dst*8+rel]++ ; erec = {src, w_norm} -----
__global__ void fill2_kernel(const int* __restrict__ src, const int* __restrict__ dst,
                             const int* __restrict__ et, const float* __restrict__ ew,
                             const float* __restrict__ mm, int* __restrict__ rp2,
                             int2* __restrict__ erec, int E) {
    int e = blockIdx.x * blockDim.x + threadIdx.x;
    if (e >= E) return;
    int pos = atomicAdd(&rp2[dst[e] * R_NUM + et[e]], 1);
    float mn = mm[0], mx = mm[1];
    erec[pos] = make_int2(src[e], __float_as_int((ew[e] - mn) / (mx - mn + 1e-8f)));
}

// =====================================================================
// Fused layer: per block of 64 dst nodes, loop r=0..8:
//   stage Wt[r] (coalesced) -> LDS ; gather y-rows (rel r) -> LDS ;
//   MFMA accumulate. Epilogue: bias(+relu), LDS-transpose, coalesced store.
// y[n][r] = invc[n] * sum_{e in (n,r)} w_e * inp[src_e]   (r=8: inp[n])
// out[n]  = sum_r y[n][r] @ Wt[r] + bias
// MFMA roles (verified R4/R5): A=Wt frag (lane&15 -> out-col), B=y frag
// (lane&15 -> node), D: col=node, row=quad*4+i -> out-col.
// =====================================================================
template <int NCOL, bool RELU, bool OUTB>
__global__ __launch_bounds__(256) void fused_layer(
    const unsigned short* __restrict__ inp,   // N x 128 bf16
    const unsigned short* __restrict__ Wt,    // 9 x NCOL x 128 bf16
    const int* __restrict__ rp2, const int2* __restrict__ erec,
    const float* __restrict__ invc, const float* __restrict__ bias,
    unsigned short* __restrict__ outb, float* __restrict__ outf, int N)
{
    constexpr int NT = NCOL / 16;
    // rows padded to 132 shorts (264 B) -> <=4-way bank conflicts on b64 reads
    __shared__ unsigned short smem[(64 + NCOL) * 132];
    unsigned short* ys  = smem;              // 64 x 132
    unsigned short* wsd = smem + 64 * 132;   // NCOL x 132

    const int tid = threadIdx.x;
    const int w = tid >> 6, lane = tid & 63;
    const int quad = lane >> 4, l15 = lane & 15;
    const int n0 = blockIdx.x * 64;

    // gather-phase mapping: 4 threads per node, each 32 channels
    const int gn = tid >> 2;
    const int gq = tid & 3;
    const int gnode = n0 + gn;
    const bool gvalid = gnode < N;
    const float ginv = gvalid ? invc[gnode] : 0.f;

    f32x4 acc[NT];
#pragma unroll
    for (int nt = 0; nt < NT; ++nt) acc[nt] = (f32x4){0.f, 0.f, 0.f, 0.f};

    for (int r = 0; r < 9; ++r) {
        // ---- stage Wt[r] -> wsd (global reads fully coalesced) ----
#pragma unroll
        for (int it = 0; it < NCOL / 16; ++it) {
            int u = tid + it * 256;
            int row = u >> 4, seg = u & 15;
            V8 v;
            v.v = *(const bf16x8*)(Wt + ((size_t)r * NCOL + row) * 128 + seg * 8);
            *(short4*)&wsd[row * 132 + seg * 8]     = v.h[0];
            *(short4*)&wsd[row * 132 + seg * 8 + 4] = v.h[1];
        }
        // ---- gather y-row slice for this r ----
        if (gvalid) {
            if (r == 8) {
                const unsigned short* srow = inp + (size_t)gnode * 128 + gq * 32;
#pragma unroll
                for (int c4 = 0; c4 < 4; ++c4) {
                    V8 v; v.v = *(const bf16x8*)(srow + c4 * 8);
                    *(short4*)&ys[gn * 132 + gq * 32 + c4 * 8]     = v.h[0];
                    *(short4*)&ys[gn * 132 + gq * 32 + c4 * 8 + 4] = v.h[1];
                }
            } else {
                int i = gnode * R_NUM + r;
                int beg = (i == 0) ? 0 : rp2[i - 1];
                int end = rp2[i];
                float a[32];
#pragma unroll
                for (int c = 0; c < 32; ++c) a[c] = 0.f;
                for (int k = beg; k < end; ++k) {
                    int2 e = erec[k];
                    float wgt = __int_as_float(e.y);
                    const unsigned short* row = inp + (size_t)e.x * 128 + gq * 32;
#pragma unroll
                    for (int c4 = 0; c4 < 4; ++c4) {
                        V8 v; v.v = *(const bf16x8*)(row + c4 * 8);
#pragma unroll
                        for (int c = 0; c < 8; ++c)
                            a[c4 * 8 + c] += wgt * b2f((unsigned short)v.v[c]);
                    }
                }
#pragma unroll
                for (int c4 = 0; c4 < 4; ++c4) {
                    short4 lo, hi;
                    lo.x = (short)f2b(a[c4*8+0] * ginv); lo.y = (short)f2b(a[c4*8+1] * ginv);
                    lo.z = (short)f2b(a[c4*8+2] * ginv); lo.w = (short)f2b(a[c4*8+3] * ginv);
                    hi.x = (short)f2b(a[c4*8+4] * ginv); hi.y = (short)f2b(a[c4*8+5] * ginv);
                    hi.z = (short)f2b(a[c4*8+6] * ginv); hi.w = (short)f2b(a[c4*8+7] * ginv);
                    *(short4*)&ys[gn * 132 + gq * 32 + c4 * 8]     = lo;
                    *(short4*)&ys[gn * 132 + gq * 32 + c4 * 8 + 4] = hi;
                }
            }
        }
        __syncthreads();
        // ---- MFMA phase: wave w covers nodes w*16..w*16+15, all NCOL cols ----
        const unsigned short* yrow = ys + (size_t)(w * 16 + l15) * 132 + quad * 8;
#pragma unroll
        for (int k2 = 0; k2 < 4; ++k2) {
            V8 b;
            b.h[0] = *(const short4*)(yrow + k2 * 32);
            b.h[1] = *(const short4*)(yrow + k2 * 32 + 4);
#pragma unroll
            for (int nt = 0; nt < NT; ++nt) {
                const unsigned short* ar = wsd + (size_t)(nt * 16 + l15) * 132
                                           + k2 * 32 + quad * 8;
                V8 av;
                av.h[0] = *(const short4*)ar;
                av.h[1] = *(const short4*)(ar + 4);
                acc[nt] = __builtin_amdgcn_mfma_f32_16x16x32_bf16(av.v, b.v, acc[nt], 0, 0, 0);
            }
        }
        __syncthreads();
    }

    // ---- epilogue: bias (+relu), LDS transpose, coalesced store ----
    if (OUTB) {
        unsigned short* stg = smem;   // 64 x 136 (272 B rows, 16B-aligned segs)
#pragma unroll
        for (int nt = 0; nt < NT; ++nt) {
            int c0 = nt * 16 + quad * 4;
            float4 bs = *(const float4*)(bias + c0);
            float v0 = acc[nt][0] + bs.x, v1 = acc[nt][1] + bs.y;
            float v2 = acc[nt][2] + bs.z, v3 = acc[nt][3] + bs.w;
            if (RELU) {
                v0 = fmaxf(v0, 0.f); v1 = fmaxf(v1, 0.f);
                v2 = fmaxf(v2, 0.f); v3 = fmaxf(v3, 0.f);
            }
            short4 o;
            o.x = (short)f2b(v0); o.y = (short)f2b(v1);
            o.z = (short)f2b(v2); o.w = (short)f2b(v3);
            *(short4*)&stg[(w * 16 + l15) * 136 + c0] = o;
        }
        __syncthreads();
        if (gvalid) {
            const unsigned short* srow = stg + gn * 136 + gq * (NCOL / 4);
            unsigned short* drow = outb + (size_t)gnode * NCOL + gq * (NCOL / 4);
#pragma unroll
            for (int c = 0; c < NCOL / 32; ++c)
                *(bf16x8*)(drow + c * 8) = *(const bf16x8*)(srow + c * 8);
        }
    } else {
        float* stg = (float*)smem;    // 64 x 68 floats (272 B rows)
#pragma unroll
        for (int nt = 0; nt < NT; ++nt) {
            int c0 = nt * 16 + quad * 4;
            float4 bs = *(const float4*)(bias + c0);
            float v0 = acc[nt][0] + bs.x, v1 = acc[nt][1] + bs.y;
            float v2 = acc[nt][2] + bs.z, v3 = acc[nt][3] + bs.w;
            if (RELU) {
                v0 = fmaxf(v0, 0.f); v1 = fmaxf(v1, 0.f);
                v2 = fmaxf(v2, 0.f); v3 = fmaxf(v3, 0.f);
            }
            *(float4*)&stg[(w * 16 + l15) * 68 + c0] = make_float4(v0, v1, v2, v3);
        }
        __syncthreads();
        if (gvalid) {
            const float* srow = stg + gn * 68 + gq * (NCOL / 4);
            float* drow = outf + (size_t)gnode * NCOL + gq * (NCOL / 4);
#pragma unroll
            for (int c = 0; c < NCOL / 16; ++c)
                *(float4*)(drow + c * 4) = *(const float4*)(srow + c * 4);
        }
    }
}

extern "C" void kernel_launch(void* const* d_in, const int* in_sizes, int n_in,
                              void* d_out, int out_size, void* d_ws, size_t ws_size,
                              hipStream_t stream) {
    const float* x     = (const float*)d_in[0];
    const int*   ei    = (const int*)d_in[1];
    const float* ew    = (const float*)d_in[2];
    const int*   et    = (const int*)d_in[3];
    const float* W1    = (const float*)d_in[4];
    const float* root1 = (const float*)d_in[5];
    const float* bias1 = (const float*)d_in[6];
    const float* W2    = (const float*)d_in[7];
    const float* root2 = (const float*)d_in[8];
    const float* bias2 = (const float*)d_in[9];

    const int N = in_sizes[0] / F_DIM;
    const int E = in_sizes[2];
    const int M2 = N * R_NUM;
    const int* srcp = ei;
    const int* dstp = ei + E;

    // ws layout (int units unless noted):
    // mm[16] | invc[N] | deg2[8N] | rp2[8N] | bsum[256] | erec[2E int] |
    // xb[N*128 u16] | hb[N*128 u16] | wt1[9*128*128 u16] | wt2[9*64*128 u16]
    int* base = (int*)d_ws;
    float* mm    = (float*)base;
    float* invc  = (float*)(base + 16);
    int*   deg2  = base + 16 + N;
    int*   rp2   = deg2 + M2;
    int*   bsum  = rp2 + M2;
    int2*  erec  = (int2*)(bsum + 256);
    unsigned short* xb  = (unsigned short*)(bsum + 256 + 2 * E);
    unsigned short* hb  = xb + (size_t)N * 128;
    unsigned short* wt1 = hb + (size_t)N * 128;
    unsigned short* wt2 = wt1 + 9 * 128 * 128;

    const int TB = 256;
    int blocksE = (E + TB - 1) / TB;
    int blocksN = (N + TB - 1) / TB;
    int nb = (M2 + 2047) / 2048;   // 196 <= 256

    // ---- setup ----
    init_mm<<<1, 64, 0, stream>>>(mm);
    hipMemsetAsync(deg2, 0, (size_t)M2 * sizeof(int), stream);
    count_minmax<<<512, TB, 0, stream>>>(ew, dstp, et, deg2, mm, E);
    long x4 = (long)N * 128 / 4;
    convert_bf16<<<(int)((x4 + TB - 1) / TB), TB, 0, stream>>>(x, xb, x4);
    int wt1n = 9 * 128 * 128, wt2n = 9 * 64 * 128;
    conv_wt<<<(wt1n + TB - 1) / TB, TB, 0, stream>>>(W1, root1, wt1, F_DIM, H_DIM);
    conv_wt<<<(wt2n + TB - 1) / TB, TB, 0, stream>>>(W2, root2, wt2, H_DIM, O_DIM);
    scan1_kernel<<<nb, TB, 0, stream>>>(deg2, rp2, bsum, M2);
    scan2_kernel<<<1, TB, 0, stream>>>(bsum, nb);
    scan3_kernel<<<(M2 + TB - 1) / TB, TB, 0, stream>>>(rp2, bsum, M2);
    invert2_kernel<<<blocksN, TB, 0, stream>>>(deg2, invc, N);
    fill2_kernel<<<blocksE, TB, 0, stream>>>(srcp, dstp, et, ew, mm, rp2, erec, E);

    int gB = (N + 63) / 64;   // 782

    // ---- layer 1: 128 -> 128, relu, bf16 out ----
    fused_layer<H_DIM, true, true><<<gB, TB, 0, stream>>>(
        xb, wt1, rp2, erec, invc, bias1, hb, nullptr, N);
    // ---- layer 2: 128 -> 64, f32 out ----
    fused_layer<O_DIM, false, false><<<gB, TB, 0, stream>>>(
        hb, wt2, rp2, erec, invc, bias2, nullptr, (float*)d_out, N);
}

// Round 7
// 337.470 us; speedup vs baseline: 1.5301x; 1.0900x over previous
//
#include <hip/hip_runtime.h>

// Problem constants: N=50000, E=600000, F=128, H=128, O=64, R=8
#define F_DIM 128
#define H_DIM 128
#define O_DIM 64
#define R_NUM 8

typedef __attribute__((ext_vector_type(8))) short bf16x8;
typedef __attribute__((ext_vector_type(4))) float f32x4;
typedef __attribute__((ext_vector_type(8))) unsigned short u16x8;

union V8 { bf16x8 v; short4 h[2]; };

__device__ __forceinline__ unsigned short f2b(float f) {
    unsigned u = __float_as_uint(f);
    u += 0x7FFFu + ((u >> 16) & 1u);   // RNE
    return (unsigned short)(u >> 16);
}
__device__ __forceinline__ float b2f(unsigned short b) {
    return __uint_as_float(((unsigned)b) << 16);
}

// ---- fused: (dst,rel) degree count + per-block edge-weight min/max ----------
__global__ void count_minmax(const float* __restrict__ ew, const int* __restrict__ dst,
                             const int* __restrict__ et, int* __restrict__ deg2,
                             float* __restrict__ bmn, float* __restrict__ bmx, int E) {
    __shared__ float smn[256], smx[256];
    int tid = threadIdx.x;
    float mn = 1e30f, mx = -1e30f;
    for (int i = blockIdx.x * blockDim.x + tid; i < E; i += gridDim.x * blockDim.x) {
        atomicAdd(&deg2[dst[i] * R_NUM + et[i]], 1);
        float v = ew[i];
        mn = fminf(mn, v);
        mx = fmaxf(mx, v);
    }
    smn[tid] = mn; smx[tid] = mx;
    __syncthreads();
    for (int s = 128; s > 0; s >>= 1) {
        if (tid < s) {
            smn[tid] = fminf(smn[tid], smn[tid + s]);
            smx[tid] = fmaxf(smx[tid], smx[tid + s]);
        }
        __syncthreads();
    }
    if (tid == 0) { bmn[blockIdx.x] = smn[0]; bmx[blockIdx.x] = smx[0]; }
}

// ---- conversions ----
__global__ void convert_bf16(const float* __restrict__ in, unsigned short* __restrict__ out,
                             long n4) {
    long i = (long)blockIdx.x * blockDim.x + threadIdx.x;
    if (i >= n4) return;
    float4 v = ((const float4*)in)[i];
    ushort4 o;
    o.x = f2b(v.x); o.y = f2b(v.y); o.z = f2b(v.z); o.w = f2b(v.w);
    ((ushort4*)out)[i] = o;
}

// both weight stacks in one launch: Wt[r][n][k] = W[r][k][n] (r<8) / root[k][n]
__global__ void conv_weights(const float* __restrict__ W1, const float* __restrict__ root1,
                             const float* __restrict__ W2, const float* __restrict__ root2,
                             unsigned short* __restrict__ wt1,
                             unsigned short* __restrict__ wt2) {
    const int n1 = 9 * 128 * 128, n2 = 9 * 64 * 128;
    int idx = blockIdx.x * blockDim.x + threadIdx.x;
    if (idx < n1) {
        int r = idx / (128 * 128), rem = idx % (128 * 128);
        int n = rem / 128, k = rem % 128;
        float v = (r < 8) ? W1[((size_t)r * 128 + k) * 128 + n] : root1[(size_t)k * 128 + n];
        wt1[idx] = f2b(v);
    } else if (idx < n1 + n2) {
        int j = idx - n1;
        int r = j / (64 * 128), rem = j % (64 * 128);
        int n = rem / 128, k = rem % 128;
        float v = (r < 8) ? W2[((size_t)r * 128 + k) * 64 + n] : root2[(size_t)k * 64 + n];
        wt2[j] = f2b(v);
    }
}

// ---- scan1: exclusive scan of deg2 (2048/block) + fused invc (8 cells = 1 node)
__global__ void scan1_kernel(const int* __restrict__ deg, int* __restrict__ rp,
                             int* __restrict__ bsum, float* __restrict__ invc,
                             int M, int N) {
    __shared__ int s[256];
    int base = blockIdx.x * 2048;
    int t = threadIdx.x;
    int v[8]; int loc = 0;
#pragma unroll
    for (int i = 0; i < 8; ++i) {
        int idx = base + t * 8 + i;
        v[i] = (idx < M) ? deg[idx] : 0;
        loc += v[i];
    }
    int node = blockIdx.x * 256 + t;
    if (node < N) invc[node] = 1.0f / (float)max(loc, 1);
    s[t] = loc;
    __syncthreads();
    for (int off = 1; off < 256; off <<= 1) {
        int x = (t >= off) ? s[t - off] : 0;
        __syncthreads();
        s[t] += x;
        __syncthreads();
    }
    int run = s[t] - loc;
#pragma unroll
    for (int i = 0; i < 8; ++i) {
        int idx = base + t * 8 + i;
        if (idx < M) rp[idx] = run;
        run += v[i];
    }
    if (t == 255) bsum[blockIdx.x] = s[255];
}

// ---- scan2 + global min/max reduce (single block) ----
__global__ void scan2_mm(int* bsum, int nb, const float* __restrict__ bmn,
                         const float* __restrict__ bmx, float* mm) {
    __shared__ int s[256];
    __shared__ float smn[256], smx[256];
    int t = threadIdx.x;
    int v = (t < nb) ? bsum[t] : 0;
    s[t] = v;
    float mn = fminf(bmn[t], bmn[t + 256]);
    float mx = fmaxf(bmx[t], bmx[t + 256]);
    smn[t] = mn; smx[t] = mx;
    __syncthreads();
    for (int off = 1; off < 256; off <<= 1) {
        int x = (t >= off) ? s[t - off] : 0;
        __syncthreads();
        s[t] += x;
        __syncthreads();
    }
    if (t < nb) bsum[t] = s[t] - v;
    for (int r = 128; r > 0; r >>= 1) {
        if (t < r) {
            smn[t] = fminf(smn[t], smn[t + r]);
            smx[t] = fmaxf(smx[t], smx[t + r]);
        }
        __syncthreads();
    }
    if (t == 0) { mm[0] = smn[0]; mm[1] = smx[0]; }
}

__global__ void scan3_kernel(int* __restrict__ rp, const int* __restrict__ bsum, int M) {
    int i = blockIdx.x * blockDim.x + threadIdx.x;
    if (i < M) rp[i] += bsum[i >> 11];
}

// ---- CSR fill: pos = rp2[dst*8+rel]++ ; erec = {src, w_norm} ----
__global__ void fill2_kernel(const int* __restrict__ src, const int* __restrict__ dst,
                             const int* __restrict__ et, const float* __restrict__ ew,
                             const float* __restrict__ mm, int* __restrict__ rp2,
                             int2* __restrict__ erec, int E) {
    int e = blockIdx.x * blockDim.x + threadIdx.x;
    if (e >= E) return;
    int pos = atomicAdd(&rp2[dst[e] * R_NUM + et[e]], 1);
    float mn = mm[0], mx = mm[1];
    erec[pos] = make_int2(src[e], __float_as_int((ew[e] - mn) / (mx - mn + 1e-8f)));
}

// ---- gather: y[n][r] = invc[n] * sum_{e in (n,r)} w * inp[src], r<8 ----------
// 16 lanes per (n,r) group, 8 channels each. Reads: 256B/edge line-aligned;
// writes fully coalesced. No barriers -> pure TLP latency hiding.
__global__ __launch_bounds__(256) void gather_y(
    const int* __restrict__ rp2, const int2* __restrict__ erec,
    const unsigned short* __restrict__ inp, const float* __restrict__ invc,
    unsigned short* __restrict__ y, int N) {
    int gid = blockIdx.x * blockDim.x + threadIdx.x;
    int grp = gid >> 4;
    int n = grp >> 3;
    if (n >= N) return;
    int r = grp & 7;
    int j = (gid & 15) * 8;
    int i = n * R_NUM + r;
    int beg = (i == 0) ? 0 : rp2[i - 1];
    int end = rp2[i];
    float acc[8] = {0.f, 0.f, 0.f, 0.f, 0.f, 0.f, 0.f, 0.f};
    for (int k = beg; k < end; ++k) {
        int2 e = erec[k];
        float w = __int_as_float(e.y);
        const u16x8 v = *(const u16x8*)(inp + (size_t)e.x * 128 + j);
#pragma unroll
        for (int c = 0; c < 8; ++c) acc[c] += w * b2f(v[c]);
    }
    float inv = invc[n];
    u16x8 o;
#pragma unroll
    for (int c = 0; c < 8; ++c) o[c] = f2b(acc[c] * inv);
    *(u16x8*)(y + ((size_t)n * R_NUM + r) * 128 + j) = o;
}

// =====================================================================
// gemm_y: out[n] = sum_{r<8} y[n][r] @ Wt[r] + inp[n] @ Wt[8] + bias
// Block = 64 nodes. Per r: stage Wt[r] + y-slice into LDS (coalesced),
// then MFMA from LDS (132-short padded rows -> free 2-way conflicts).
// MFMA roles (verified R4-R6): A=Wt frag, B=y frag, D: col=node,
// row=quad*4+i=out-col. Epilogue: bias(+relu), LDS transpose, coalesced.
// =====================================================================
template <int NCOL, bool RELU, bool OUTB>
__global__ __launch_bounds__(256) void gemm_y(
    const unsigned short* __restrict__ y,     // N x 8 x 128 bf16
    const unsigned short* __restrict__ inp,   // N x 128 bf16 (self/root rows)
    const unsigned short* __restrict__ Wt,    // 9 x NCOL x 128 bf16
    const float* __restrict__ bias,
    unsigned short* __restrict__ outb, float* __restrict__ outf, int N)
{
    constexpr int NT = NCOL / 16;
    __shared__ unsigned short smem[64 * 132 + NCOL * 132];
    unsigned short* ys  = smem;              // 64 x 132
    unsigned short* wsd = smem + 64 * 132;   // NCOL x 132

    const int tid = threadIdx.x;
    const int w = tid >> 6, lane = tid & 63;
    const int quad = lane >> 4, l15 = lane & 15;
    const int n0 = blockIdx.x * 64;

    f32x4 acc[NT];
#pragma unroll
    for (int nt = 0; nt < NT; ++nt) acc[nt] = (f32x4){0.f, 0.f, 0.f, 0.f};

    for (int r = 0; r < 9; ++r) {
        // stage Wt[r] (NCOL x 128): coalesced 16B/lane
#pragma unroll
        for (int it = 0; it < NCOL / 16; ++it) {
            int u = tid + it * 256;
            int row = u >> 4, seg = u & 15;
            V8 v;
            v.v = *(const bf16x8*)(Wt + ((size_t)r * NCOL + row) * 128 + seg * 8);
            *(short4*)&wsd[row * 132 + seg * 8]     = v.h[0];
            *(short4*)&wsd[row * 132 + seg * 8 + 4] = v.h[1];
        }
        // stage y-slice (64 nodes x 128): r<8 from y, r==8 from inp
#pragma unroll
        for (int it = 0; it < 4; ++it) {
            int u = tid + it * 256;
            int row = u >> 4, seg = u & 15;
            int node = n0 + row;
            if (node >= N) node = N - 1;
            const unsigned short* src = (r < 8)
                ? y + ((size_t)node * R_NUM + r) * 128 + seg * 8
                : inp + (size_t)node * 128 + seg * 8;
            V8 v; v.v = *(const bf16x8*)src;
            *(short4*)&ys[row * 132 + seg * 8]     = v.h[0];
            *(short4*)&ys[row * 132 + seg * 8 + 4] = v.h[1];
        }
        __syncthreads();
        // MFMA: wave w -> nodes w*16..+15, all NCOL cols
        const unsigned short* yrow = ys + (size_t)(w * 16 + l15) * 132 + quad * 8;
#pragma unroll
        for (int k2 = 0; k2 < 4; ++k2) {
            V8 b;
            b.h[0] = *(const short4*)(yrow + k2 * 32);
            b.h[1] = *(const short4*)(yrow + k2 * 32 + 4);
#pragma unroll
            for (int nt = 0; nt < NT; ++nt) {
                const unsigned short* ar = wsd + (size_t)(nt * 16 + l15) * 132
                                           + k2 * 32 + quad * 8;
                V8 av;
                av.h[0] = *(const short4*)ar;
                av.h[1] = *(const short4*)(ar + 4);
                acc[nt] = __builtin_amdgcn_mfma_f32_16x16x32_bf16(av.v, b.v, acc[nt], 0, 0, 0);
            }
        }
        __syncthreads();
    }

    // epilogue: bias (+relu), LDS transpose, coalesced store (4 thr/node)
    const int gn = tid >> 2, gq = tid & 3;
    const int gnode = n0 + gn;
    if (OUTB) {
        unsigned short* stg = smem;   // 64 x 136
#pragma unroll
        for (int nt = 0; nt < NT; ++nt) {
            int c0 = nt * 16 + quad * 4;
            float4 bs = *(const float4*)(bias + c0);
            float v0 = acc[nt][0] + bs.x, v1 = acc[nt][1] + bs.y;
            float v2 = acc[nt][2] + bs.z, v3 = acc[nt][3] + bs.w;
            if (RELU) {
                v0 = fmaxf(v0, 0.f); v1 = fmaxf(v1, 0.f);
                v2 = fmaxf(v2, 0.f); v3 = fmaxf(v3, 0.f);
            }
            short4 o;
            o.x = (short)f2b(v0); o.y = (short)f2b(v1);
            o.z = (short)f2b(v2); o.w = (short)f2b(v3);
            *(short4*)&stg[(w * 16 + l15) * 136 + c0] = o;
        }
        __syncthreads();
        if (gnode < N) {
            const unsigned short* srow = stg + gn * 136 + gq * (NCOL / 4);
            unsigned short* drow = outb + (size_t)gnode * NCOL + gq * (NCOL / 4);
#pragma unroll
            for (int c = 0; c < NCOL / 32; ++c)
                *(bf16x8*)(drow + c * 8) = *(const bf16x8*)(srow + c * 8);
        }
    } else {
        float* stg = (float*)smem;    // 64 x 68 floats
#pragma unroll
        for (int nt = 0; nt < NT; ++nt) {
            int c0 = nt * 16 + quad * 4;
            float4 bs = *(const float4*)(bias + c0);
            float v0 = acc[nt][0] + bs.x, v1 = acc[nt][1] + bs.y;
            float v2 = acc[nt][2] + bs.z, v3 = acc[nt][3] + bs.w;
            if (RELU) {
                v0 = fmaxf(v0, 0.f); v1 = fmaxf(v1, 0.f);
                v2 = fmaxf(v2, 0.f); v3 = fmaxf(v3, 0.f);
            }
            *(float4*)&stg[(w * 16 + l15) * 68 + c0] = make_float4(v0, v1, v2, v3);
        }
        __syncthreads();
        if (gnode < N) {
            const float* srow = stg + gn * 68 + gq * (NCOL / 4);
            float* drow = outf + (size_t)gnode * NCOL + gq * (NCOL / 4);
#pragma unroll
            for (int c = 0; c < NCOL / 16; ++c)
                *(float4*)(drow + c * 4) = *(const float4*)(srow + c * 4);
        }
    }
}

extern "C" void kernel_launch(void* const* d_in, const int* in_sizes, int n_in,
                              void* d_out, int out_size, void* d_ws, size_t ws_size,
                              hipStream_t stream) {
    const float* x     = (const float*)d_in[0];
    const int*   ei    = (const int*)d_in[1];
    const float* ew    = (const float*)d_in[2];
    const int*   et    = (const int*)d_in[3];
    const float* W1    = (const float*)d_in[4];
    const float* root1 = (const float*)d_in[5];
    const float* bias1 = (const float*)d_in[6];
    const float* W2    = (const float*)d_in[7];
    const float* root2 = (const float*)d_in[8];
    const float* bias2 = (const float*)d_in[9];

    const int N = in_sizes[0] / F_DIM;
    const int E = in_sizes[2];
    const int M2 = N * R_NUM;
    const int* srcp = ei;
    const int* dstp = ei + E;

    // ws layout (int units unless noted):
    // mm[16] | invc[N] | deg2[8N] | rp2[8N] | bsum[256] | bmn[512] | bmx[512] |
    // erec[2E] | xb[N*128 u16] | hb[N*128 u16] | wt1[9*128*128 u16] |
    // wt2[9*64*128 u16] | y[N*1024 u16]      (~140 MB)
    int* base = (int*)d_ws;
    float* mm    = (float*)base;
    float* invc  = (float*)(base + 16);
    int*   deg2  = base + 16 + N;
    int*   rp2   = deg2 + M2;
    int*   bsum  = rp2 + M2;
    float* bmn   = (float*)(bsum + 256);
    float* bmx   = bmn + 512;
    int2*  erec  = (int2*)(bmx + 512);
    unsigned short* xb  = (unsigned short*)((int*)erec + 2 * E);
    unsigned short* hb  = xb + (size_t)N * 128;
    unsigned short* wt1 = hb + (size_t)N * 128;
    unsigned short* wt2 = wt1 + 9 * 128 * 128;
    unsigned short* y   = wt2 + 9 * 64 * 128;   // N * 8 * 128

    const int TB = 256;
    int blocksE = (E + TB - 1) / TB;
    int nb = (M2 + 2047) / 2048;   // 196 <= 256

    // ---- setup (8 launches) ----
    hipMemsetAsync(deg2, 0, (size_t)M2 * sizeof(int), stream);
    count_minmax<<<512, TB, 0, stream>>>(ew, dstp, et, deg2, bmn, bmx, E);
    long x4 = (long)N * 128 / 4;
    convert_bf16<<<(int)((x4 + TB - 1) / TB), TB, 0, stream>>>(x, xb, x4);
    int wtot = 9 * 128 * 128 + 9 * 64 * 128;
    conv_weights<<<(wtot + TB - 1) / TB, TB, 0, stream>>>(W1, root1, W2, root2, wt1, wt2);
    scan1_kernel<<<nb, TB, 0, stream>>>(deg2, rp2, bsum, invc, M2, N);
    scan2_mm<<<1, TB, 0, stream>>>(bsum, nb, bmn, bmx, mm);
    scan3_kernel<<<(M2 + TB - 1) / TB, TB, 0, stream>>>(rp2, bsum, M2);
    fill2_kernel<<<blocksE, TB, 0, stream>>>(srcp, dstp, et, ew, mm, rp2, erec, E);

    int gatB = (int)(((long)N * R_NUM * 16 + TB - 1) / TB);   // 25000
    int gB = (N + 63) / 64;                                    // 782

    // ---- layer 1: 128 -> 128, relu, bf16 out ----
    gather_y<<<gatB, TB, 0, stream>>>(rp2, erec, xb, invc, y, N);
    gemm_y<H_DIM, true, true><<<gB, TB, 0, stream>>>(y, xb, wt1, bias1, hb, nullptr, N);
    // ---- layer 2: 128 -> 64, f32 out ----
    gather_y<<<gatB, TB, 0, stream>>>(rp2, erec, hb, invc, y, N);
    gemm_y<O_DIM, false, false><<<gB, TB, 0, stream>>>(y, hb, wt2, bias2, nullptr,
                                                       (float*)d_out, N);
}